// Round 9
// baseline (64.275 us; speedup 1.0000x reference)
//
#include <hip/hip_runtime.h>
#include <math.h>

// ---------------- problem constants ----------------
#define NROWS 32768   // B*T independent rows (alpha=exp(-50): scan decouples, verified R1)
#define NK 256        // IN_F
#define NF 256        // F
#define NT_SEQ 256    // T
#define MTILE 32      // rows per block (R9: LDS-free, 4 waves x [32 rows x 64 cols])
#define TAU 5e-4f     // fp16-split vs fp64 ambiguity band (validated R5..R8: absmax 0.0)

// Verified facts (R1/R3/R5..R8, absmax == 0.0):
//  * v_mem(t) == cur(t) exactly in the reference's own arithmetic.
//  * LN of binary s collapses: mu = k/256 exact, var = mu(1-mu).
//  * fp64 dot reproduces the np reference's spike decisions exactly.
//  * MFMA fragment mapping (A: row=lane&15, k=(lane>>4)*8+j; B: col=lane&15;
//    C/D: col=lane&15, row=(lane>>4)*4+reg) correct.
//  * fp16 2+2 split (a ~ ah + al/2048, W*16 ~ b1 + b2/2048), 3 MFMA products,
//    TAU=5e-4 recheck band: exact.
// R9: drop the LDS A-panel entirely. A-fragments load straight from global
// (two float4 per lane, 128B-aligned row segments), split to fp16 in
// registers. No barriers in the hot loop; LDS only for the tiny LN combine.

typedef __attribute__((ext_vector_type(4))) float f32x4;
typedef __attribute__((ext_vector_type(8))) _Float16 f16x8;

__device__ __forceinline__ unsigned short f16_bits(float x) {
    return __builtin_bit_cast(unsigned short, (_Float16)x);   // RNE cvt
}

// ---- k0: split W*16 into 2 fp16 comps, MFMA-B-fragment order ----
// wt[comp][ks][chunk][col][j] shorts; comp stride 65536, ks 8192, chunk 2048.
__global__ void split_w(const float* __restrict__ W, unsigned short* __restrict__ wt) {
    const int k = blockIdx.x;       // 0..255
    const int col = threadIdx.x;    // 0..255
    const float w16 = W[k * NF + col] * 16.0f;     // exact scale by 2^4
    const _Float16 h1 = (_Float16)w16;             // RNE
    const float r = (w16 - (float)h1) * 2048.0f;   // exact (Sterbenz; *2^11)
    const _Float16 h2 = (_Float16)r;               // RNE
    const int ks = k >> 5, chunk = (k >> 3) & 3, j = k & 7;
    const int base = ((ks * 4 + chunk) * 2048) + col * 8 + j;
    wt[base] = __builtin_bit_cast(unsigned short, h1);
    wt[base + 65536] = __builtin_bit_cast(unsigned short, h2);
}

// ---- k1: LDS-free split-GEMM + spike + exact recheck + closed-form LN ----
__global__ __launch_bounds__(256, 3)
void lif_main(const float* __restrict__ spikes,
              const float* __restrict__ W,
              const float* __restrict__ bias,
              const float* __restrict__ ln_scale,
              const float* __restrict__ ln_bias,
              const unsigned short* __restrict__ wt,
              float* __restrict__ out)
{
    __shared__ unsigned int bits[MTILE][8];   // 256-bit row masks (1 KB)
    __shared__ float rinv_s[MTILE], mu_s[MTILE];
    __shared__ unsigned int elist[64];        // in-band worklist
    __shared__ int ecnt;

    const int tid = threadIdx.x;
    const int lane = tid & 63;
    const int wid = tid >> 6;                 // 0..3: cols [wid*64, +64)
    const int row0 = blockIdx.x * MTILE;

    if (tid == 0) ecnt = 0;
    __syncthreads();

    // A-fragment source: lane reads spikes[row0 + mt*16 + (lane&15)]
    //                               [ks*32 + (lane>>4)*8 + 0..7]  (fp32 x8)
    const float* a_base = spikes + (size_t)(row0 + (lane & 15)) * NK + (lane >> 4) * 8;
    // B-fragment base (pre-permuted): + ks*8192 + nt*128, comp offset 65536
    const int b_base = (lane >> 4) * 2048 + (wid * 64 + (lane & 15)) * 8;

    f32x4 acc0[2][4], acc1[2][4];   // [mt][nt]
    {
        const f32x4 z = {0.f, 0.f, 0.f, 0.f};
        #pragma unroll
        for (int mt = 0; mt < 2; ++mt)
            #pragma unroll
            for (int nt = 0; nt < 4; ++nt) { acc0[mt][nt] = z; acc1[mt][nt] = z; }
    }

    #pragma unroll 2
    for (int ks = 0; ks < 8; ++ks) {
        // ---- A: global -> regs -> fp16 2+2 split (no LDS, no barrier) ----
        f16x8 ah[2], al[2];
        #pragma unroll
        for (int mt = 0; mt < 2; ++mt) {
            const float* p = a_base + (size_t)(mt * 16) * NK + ks * 32;
            const float4 u = *reinterpret_cast<const float4*>(p);
            const float4 v = *reinterpret_cast<const float4*>(p + 4);
            const float fv[8] = {u.x, u.y, u.z, u.w, v.x, v.y, v.z, v.w};
            #pragma unroll
            for (int e = 0; e < 8; ++e) {
                const _Float16 h = (_Float16)fv[e];          // RNE
                ah[mt][e] = h;
                al[mt][e] = (_Float16)((fv[e] - (float)h) * 2048.0f);
            }
        }
        // ---- B (L2-resident) + 24 MFMA ----
        #pragma unroll
        for (int nt = 0; nt < 4; ++nt) {
            const f16x8 b1 = *reinterpret_cast<const f16x8*>(
                wt + ks * 8192 + b_base + nt * 128);
            const f16x8 b2 = *reinterpret_cast<const f16x8*>(
                wt + 65536 + ks * 8192 + b_base + nt * 128);
            #pragma unroll
            for (int mt = 0; mt < 2; ++mt) {
                acc0[mt][nt] = __builtin_amdgcn_mfma_f32_16x16x32_f16(ah[mt], b1, acc0[mt][nt], 0, 0, 0);
                acc1[mt][nt] = __builtin_amdgcn_mfma_f32_16x16x32_f16(ah[mt], b2, acc1[mt][nt], 0, 0, 0);
                acc1[mt][nt] = __builtin_amdgcn_mfma_f32_16x16x32_f16(al[mt], b1, acc1[mt][nt], 0, 0, 0);
            }
        }
    }

    // ---- decisions; in-band elements -> worklist ----
    unsigned int smask[2] = {0u, 0u};   // bit nt*4+reg
    #pragma unroll
    for (int mt = 0; mt < 2; ++mt)
        #pragma unroll
        for (int nt = 0; nt < 4; ++nt) {
            const int gcol = wid * 64 + nt * 16 + (lane & 15);
            const float bv = bias[gcol];
            #pragma unroll
            for (int reg = 0; reg < 4; ++reg) {
                // v = (acc0 + acc1/2048) / 16 + bias
                const float v = fmaf(acc1[mt][nt][reg], 4.8828125e-4f,
                                     acc0[mt][nt][reg]) * 0.0625f + bv;
                if ((v - 0.5f) > 0.0f) smask[mt] |= 1u << (nt * 4 + reg);
                if (__builtin_expect(fabsf(v - 0.5f) < TAU, 0)) {
                    const int rl = mt * 16 + (lane >> 4) * 4 + reg;
                    const int ei = atomicAdd(&ecnt, 1);
                    if (ei < 64) elist[ei] = (unsigned int)((rl << 8) | gcol);
                }
            }
        }

    // ---- assemble row masks (each wave owns 2 words per row) ----
    #pragma unroll
    for (int mt = 0; mt < 2; ++mt)
        #pragma unroll
        for (int reg = 0; reg < 4; ++reg) {
            unsigned long long m[4];
            #pragma unroll
            for (int nt = 0; nt < 4; ++nt)
                m[nt] = __ballot((smask[mt] >> (nt * 4 + reg)) & 1u);
            if (lane < 4) {
                const int g = lane;
                const unsigned int w0 =
                    (unsigned int)((m[0] >> (g * 16)) & 0xFFFFull) |
                    ((unsigned int)((m[1] >> (g * 16)) & 0xFFFFull) << 16);
                const unsigned int w1 =
                    (unsigned int)((m[2] >> (g * 16)) & 0xFFFFull) |
                    ((unsigned int)((m[3] >> (g * 16)) & 0xFFFFull) << 16);
                const int rl = mt * 16 + g * 4 + reg;
                bits[rl][wid * 2 + 0] = w0;
                bits[rl][wid * 2 + 1] = w1;
            }
        }
    __syncthreads();

    // ---- exact fp64 recheck of in-band elements (wave-parallel, rare) ----
    const int ne = min(ecnt, 64);
    for (int e = wid; e < ne; e += 4) {
        const unsigned int pk = elist[e];
        const int rl = (int)(pk >> 8), gcol = (int)(pk & 255u);
        const float* sr = spikes + (size_t)(row0 + rl) * NK;
        const float* wc = W + gcol;
        const int k0 = lane * 4;
        const double p0 = (double)sr[k0 + 0] * (double)wc[(size_t)(k0 + 0) * NF];
        const double p1 = (double)sr[k0 + 1] * (double)wc[(size_t)(k0 + 1) * NF];
        const double p2 = (double)sr[k0 + 2] * (double)wc[(size_t)(k0 + 2) * NF];
        const double p3 = (double)sr[k0 + 3] * (double)wc[(size_t)(k0 + 3) * NF];
        double pl = (p0 + p1) + (p2 + p3);
        #pragma unroll
        for (int off = 32; off > 0; off >>= 1) pl += __shfl_down(pl, off);
        if (lane == 0) {
            const double vex = pl + (double)bias[gcol];
            const bool sex = (vex - 0.5) > 0.0;
            const bool spv = (bits[rl][gcol >> 5] >> (gcol & 31)) & 1u;
            if (sex != spv) atomicXor(&bits[rl][gcol >> 5], 1u << (gcol & 31));
        }
    }
    __syncthreads();

    // ---- per-row stats (identical double math to R1..R8) ----
    if (tid < MTILE) {
        int kc = 0;
        #pragma unroll
        for (int w = 0; w < 8; ++w) kc += __popc(bits[tid][w]);
        const double mu = (double)kc * (1.0 / 256.0);
        const double var = mu * (1.0 - mu);
        rinv_s[tid] = (float)(1.0 / sqrt(var + 1e-6));
        mu_s[tid] = (float)mu;
    }
    __syncthreads();

    // ---- LN epilogue + coalesced float4 store ----
    const int orow = tid >> 3;           // 0..31
    const int of0 = (tid & 7) * 4;       // 0..28
    const int grow = row0 + orow;
    const int t = grow & (NT_SEQ - 1);
    const float rinv = rinv_s[orow];
    const float muf = mu_s[orow];
    #pragma unroll
    for (int j = 0; j < 8; ++j) {
        const int f = of0 + j * 32;
        const unsigned int wb = bits[orow][j];   // f>>5 == j since of0 < 32
        const int sh = of0;
        const float4 g4 = *reinterpret_cast<const float4*>(&ln_scale[t * NF + f]);
        const float4 b4 = *reinterpret_cast<const float4*>(&ln_bias[t * NF + f]);
        float4 o;
        const float s0 = ((wb >> (sh + 0)) & 1u) ? 1.0f : 0.0f;
        const float s1 = ((wb >> (sh + 1)) & 1u) ? 1.0f : 0.0f;
        const float s2 = ((wb >> (sh + 2)) & 1u) ? 1.0f : 0.0f;
        const float s3 = ((wb >> (sh + 3)) & 1u) ? 1.0f : 0.0f;
        o.x = (s0 - muf) * rinv * g4.x + b4.x;
        o.y = (s1 - muf) * rinv * g4.y + b4.y;
        o.z = (s2 - muf) * rinv * g4.z + b4.z;
        o.w = (s3 - muf) * rinv * g4.w + b4.w;
        *reinterpret_cast<float4*>(&out[(size_t)grow * NF + f]) = o;
    }
}

extern "C" void kernel_launch(void* const* d_in, const int* in_sizes, int n_in,
                              void* d_out, int out_size, void* d_ws, size_t ws_size,
                              hipStream_t stream) {
    const float* spikes   = (const float*)d_in[0];
    const float* W        = (const float*)d_in[1];
    const float* bias     = (const float*)d_in[2];
    const float* ln_scale = (const float*)d_in[3];
    const float* ln_bias  = (const float*)d_in[4];
    float* out = (float*)d_out;
    unsigned short* wt = (unsigned short*)d_ws;   // 256 KB

    split_w<<<dim3(256), dim3(256), 0, stream>>>(W, wt);
    lif_main<<<dim3(NROWS / MTILE), dim3(256), 0, stream>>>(
        spikes, W, bias, ln_scale, ln_bias, wt, out);
}